// Round 2
// baseline (375.441 us; speedup 1.0000x reference)
//
#include <hip/hip_runtime.h>
#include <hip/hip_fp16.h>
#include <math.h>

static constexpr float BN_EPS = 1e-5f;
static constexpr float NEG = 0.2f;

typedef float f32x4 __attribute__((ext_vector_type(4)));
typedef _Float16 h16x2 __attribute__((ext_vector_type(2)));
typedef _Float16 h16x8 __attribute__((ext_vector_type(8)));

// ---------------- hist + W-pack fused (independent work, chain start) --------
// blocks 0..191: pack layers 0-2 (NTT=16, M=128); 192..199: pack layer 3
// (NTT=2, M=16); blocks 200+: dst histogram (self-loop for e >= E).

__global__ __launch_bounds__(256) void hist_pack(
    const int* __restrict__ ei, int E, int n, int* __restrict__ cnt,
    const float* __restrict__ W0l, const float* __restrict__ W0r,
    const float* __restrict__ W1l, const float* __restrict__ W1r,
    const float* __restrict__ W2l, const float* __restrict__ W2r,
    const float* __restrict__ W3l, const float* __restrict__ W3r,
    __half* __restrict__ pk0, __half* __restrict__ pk1,
    __half* __restrict__ pk2, __half* __restrict__ pk3) {
    int b = blockIdx.x;
    if (b < 200) {
        if (threadIdx.x >= 64) return;
        const float *Wl, *Wr;
        __half* packed;
        int tile, NTT, M;
        if (b < 192) {
            int layer = b >> 6;
            tile = b & 63;
            NTT = 16; M = 128;
            Wl = (layer == 0) ? W0l : (layer == 1) ? W1l : W2l;
            Wr = (layer == 0) ? W0r : (layer == 1) ? W1r : W2r;
            packed = (layer == 0) ? pk0 : (layer == 1) ? pk1 : pk2;
        } else {
            tile = b - 192;
            NTT = 2; M = 16;
            Wl = W3l; Wr = W3r; packed = pk3;
        }
        int NT = NTT >> 1;
        int gnt = tile % NTT;
        int kt = tile / NTT;
        int l = threadIdx.x;
        const float* W = (gnt < NT) ? Wl : Wr;
        int col = (gnt % NT) * 16 + (l & 15);
        int krow = kt * 32 + ((l >> 4) << 3);
        size_t base = (size_t)tile * 512 + (size_t)l * 8;
#pragma unroll
        for (int j = 0; j < 8; j++)
            packed[base + j] = __float2half(W[(size_t)(krow + j) * M + col]);
    } else {
        int e = (b - 200) * 256 + threadIdx.x;
        int ET = E + n;
        if (e >= ET) return;
        int d = (e < E) ? ei[E + e] : (e - E);
        atomicAdd(&cnt[d], 1);
    }
}

// ---------------- CSR scan chain (kernel boundaries are the cheap barrier) ---
// 256-thread scan body (4 elements/thread) so it can co-dispatch with the
// layer-0 GEMM without capping the GEMM's VGPR budget.

__device__ __forceinline__ void scan_block_body256(
    const int* __restrict__ cnt, int* __restrict__ rowptr,
    int* __restrict__ bsums, int n, int bid, int* s) {
    int t = threadIdx.x;               // 0..255
    int base = bid * 1024 + t * 4;
    int v0 = 0, v1 = 0, v2 = 0, v3 = 0;
    if (base + 3 < n) {
        v0 = cnt[base];     v1 = cnt[base + 1];
        v2 = cnt[base + 2]; v3 = cnt[base + 3];
    } else {
        if (base < n)     v0 = cnt[base];
        if (base + 1 < n) v1 = cnt[base + 1];
        if (base + 2 < n) v2 = cnt[base + 2];
        if (base + 3 < n) v3 = cnt[base + 3];
    }
    int p1 = v0 + v1, p2 = p1 + v2, p3 = p2 + v3;
    s[t] = p3;
    __syncthreads();
    for (int d = 1; d < 256; d <<= 1) {
        int tt = (t >= d) ? s[t - d] : 0;
        __syncthreads();
        s[t] += tt;
        __syncthreads();
    }
    int ex = s[t] - p3;                // exclusive offset for this thread
    if (base < n)     rowptr[base + 1] = ex + v0;
    if (base + 1 < n) rowptr[base + 2] = ex + p1;
    if (base + 2 < n) rowptr[base + 3] = ex + p2;
    if (base + 3 < n) rowptr[base + 4] = ex + p3;
    if (t == 255) bsums[bid] = s[255];
}

// fused: each block redundantly wave-scans the (raw) per-block sums, picks its
// own exclusive offset, then adds. Replaces scan_bsums + scan_add (nb <= 64).
__global__ __launch_bounds__(1024) void scan_add2(
    int* __restrict__ rowptr, const int* __restrict__ bsums, int n, int nb) {
    __shared__ int sex;
    if (threadIdx.x < 64) {
        int L = threadIdx.x;
        int v = (L < nb) ? bsums[L] : 0;
#pragma unroll
        for (int d = 1; d < 64; d <<= 1) {
            int t = __shfl_up(v, d);
            if (L >= d) v += t;
        }
        int ex = __shfl_up(v, 1);
        if (L == 0) ex = 0;
        if (L == (int)blockIdx.x) sex = ex;
    }
    __syncthreads();
    int i = blockIdx.x * 1024 + threadIdx.x;
    if (i < n) rowptr[i + 1] += sex;
    if (i == 0) rowptr[0] = 0;
}

__global__ void scatter_kernel(const int* __restrict__ ei, int E, int n,
                               const int* __restrict__ rowptr, int* __restrict__ fill,
                               int* __restrict__ col) {
    int e = blockIdx.x * blockDim.x + threadIdx.x;
    int ET = E + n;
    if (e >= ET) return;
    int s, d;
    if (e < E) { s = ei[e]; d = ei[E + e]; } else { s = e - E; d = s; }
    int pos = atomicAdd(&fill[d], 1);
    col[rowptr[d] + pos] = s;
}

// ---------------- fp16 MFMA dual GEMM: Y1 = X@Wl, Y2 = X@Wr (M=128 each) ----
// body as a device fn so layer 0 can co-dispatch with scan_block.

template <bool FIRST>
__device__ __forceinline__ void gemm_body(
    const __half* __restrict__ xh, const float* __restrict__ xf,
    const __half* __restrict__ packed,
    __half* __restrict__ Y1, __half* __restrict__ Y2, int n, int bid,
    _Float16* sA) {
    const int t = threadIdx.x;
    const int row0 = bid * 64;

    for (int c = t; c < 1024; c += 256) {
        int row = c >> 4;
        int off = (c & 15) * 8;
        int gr = row0 + row;
        if (gr >= n) gr = n - 1;
        if (FIRST) {
            float4 v0 = *(const float4*)&xf[(size_t)gr * 128 + off];
            float4 v1 = *(const float4*)&xf[(size_t)gr * 128 + off + 4];
            h16x8 h = {(_Float16)v0.x, (_Float16)v0.y, (_Float16)v0.z, (_Float16)v0.w,
                       (_Float16)v1.x, (_Float16)v1.y, (_Float16)v1.z, (_Float16)v1.w};
            *(h16x8*)&sA[row * 136 + off] = h;
        } else {
            *(h16x8*)&sA[row * 136 + off] = *(const h16x8*)&xh[(size_t)gr * 128 + off];
        }
    }
    __syncthreads();

    const int lane = t & 63;
    const int s = t >> 6;
    const int lr = lane & 15;
    const int kq = (lane >> 4) * 8;

    h16x8 af[4][4];                 // [rt][kt]
#pragma unroll
    for (int rt = 0; rt < 4; rt++)
#pragma unroll
        for (int kt = 0; kt < 4; kt++)
            af[rt][kt] = *(const h16x8*)&sA[(rt * 16 + lr) * 136 + kt * 32 + kq];

    f32x4 acc[4][4];                // [ntl][rt]
#pragma unroll
    for (int a = 0; a < 4; a++)
#pragma unroll
        for (int b = 0; b < 4; b++) acc[a][b] = (f32x4){0.f, 0.f, 0.f, 0.f};

#pragma unroll
    for (int kt = 0; kt < 4; kt++) {
#pragma unroll
        for (int ntl = 0; ntl < 4; ntl++) {
            int nt = s * 4 + ntl;
            h16x8 b = *(const h16x8*)&packed[((size_t)(kt * 16 + nt)) * 512 + lane * 8];
#pragma unroll
            for (int rt = 0; rt < 4; rt++)
                acc[ntl][rt] = __builtin_amdgcn_mfma_f32_16x16x32_f16(af[rt][kt], b, acc[ntl][rt], 0, 0, 0);
        }
    }

    __half* Y = (s < 2) ? Y1 : Y2;
    const int colh = (s & 1) * 64;
    const int rq = (lane >> 4) * 4;
#pragma unroll
    for (int ntl = 0; ntl < 4; ntl++) {
        int col = colh + ntl * 16 + lr;
#pragma unroll
        for (int rt = 0; rt < 4; rt++) {
#pragma unroll
            for (int g = 0; g < 4; g++) {
                int row = row0 + rt * 16 + rq + g;
                if (row < n) Y[(size_t)row * 128 + col] = __float2half(acc[ntl][rt][g]);
            }
        }
    }
}

__global__ __launch_bounds__(256) void gemm_h_big2(
    const __half* __restrict__ xh, const __half* __restrict__ packed,
    __half* __restrict__ Y1, __half* __restrict__ Y2, int n) {
    __shared__ __align__(16) char smem[64 * 136 * 2];
    gemm_body<false>(xh, nullptr, packed, Y1, Y2, n, blockIdx.x, (_Float16*)smem);
}

// fused dispatch: blocks [0, nscan) do the CSR block-scan, the rest run the
// layer-0 GEMM (both depend only on hist_pack; independent of each other).
__global__ __launch_bounds__(256) void scanblk_gemm0(
    const int* __restrict__ cnt, int* __restrict__ rowptr,
    int* __restrict__ bsums, int n, int nscan,
    const float* __restrict__ xf, const __half* __restrict__ packed,
    __half* __restrict__ Y1, __half* __restrict__ Y2) {
    __shared__ __align__(16) char smem[64 * 136 * 2];
    int b = blockIdx.x;
    if (b < nscan) {
        scan_block_body256(cnt, rowptr, bsums, n, b, (int*)smem);
    } else {
        gemm_body<true>(nullptr, xf, packed, Y1, Y2, n, b - nscan,
                        (_Float16*)smem);
    }
}

// ---------------- small fp16 GEMM for layer 3 (M=16 each, fp32 out) ----------

__global__ __launch_bounds__(256) void gemm_h_small(
    const __half* __restrict__ xh, const __half* __restrict__ packed,
    float* __restrict__ Y1, float* __restrict__ Y2, int n) {
    int lane = threadIdx.x & 63;
    int wv = blockIdx.x * 4 + (threadIdx.x >> 6);
    int row0 = wv * 16;
    if (row0 >= n) return;
    int r = row0 + (lane & 15);
    if (r >= n) r = n - 1;
    int kq = (lane >> 4) * 8;

    h16x8 af[4];
#pragma unroll
    for (int kt = 0; kt < 4; kt++)
        af[kt] = *(const h16x8*)&xh[(size_t)r * 128 + kt * 32 + kq];

    f32x4 acc[2];
    acc[0] = (f32x4){0.f, 0.f, 0.f, 0.f};
    acc[1] = (f32x4){0.f, 0.f, 0.f, 0.f};

#pragma unroll
    for (int kt = 0; kt < 4; kt++) {
#pragma unroll
        for (int nt = 0; nt < 2; nt++) {
            h16x8 b = *(const h16x8*)&packed[((size_t)(kt * 2 + nt)) * 512 + lane * 8];
            acc[nt] = __builtin_amdgcn_mfma_f32_16x16x32_f16(af[kt], b, acc[nt], 0, 0, 0);
        }
    }

    int colb = lane & 15;
    int rbase = row0 + (lane >> 4) * 4;
#pragma unroll
    for (int nt = 0; nt < 2; nt++) {
        float* Y = (nt == 0) ? Y1 : Y2;
#pragma unroll
        for (int g = 0; g < 4; g++) {
            int row = rbase + g;
            if (row < n) Y[(size_t)row * 16 + colb] = acc[nt][g];
        }
    }
}

// ---------------- Fused GATv2 aggregate (col-hoist, 16 lanes/edge) ----------
// Wave = one node. 4 groups of 16 lanes; each group owns one edge per step,
// each lane owns 8 channels (one 16B fp16 gather). One head (C=16) spans a
// PAIR of lanes -> per-head logit reduce is shfl_xor(1) ONLY. Column indices
// for a 64-edge chunk are loaded once, coalesced, and distributed via shfl so
// the gathers have no VMEM dependency ahead of them.

__device__ __forceinline__ float dot8_h(const h16x2* lp, const h16x2* ap) {
#if __has_builtin(__builtin_amdgcn_fdot2)
    float part = __builtin_amdgcn_fdot2(lp[0], ap[0], 0.f, false);
    part = __builtin_amdgcn_fdot2(lp[1], ap[1], part, false);
    part = __builtin_amdgcn_fdot2(lp[2], ap[2], part, false);
    return __builtin_amdgcn_fdot2(lp[3], ap[3], part, false);
#else
    float part = 0.f;
#pragma unroll
    for (int i = 0; i < 4; i++)
        part += (float)lp[i].x * (float)ap[i].x + (float)lp[i].y * (float)ap[i].y;
    return part;
#endif
}

__global__ __launch_bounds__(256) void agg_h(
    const __half* __restrict__ xl, const __half* __restrict__ xr,
    const int* __restrict__ rowptr, const int* __restrict__ col,
    const float* __restrict__ att, const float* __restrict__ bias,
    const float* __restrict__ g, const float* __restrict__ be,
    const float* __restrict__ bm, const float* __restrict__ bv,
    __half* __restrict__ oh, int n) {
    int v = (blockIdx.x * blockDim.x + threadIdx.x) >> 6;
    if (v >= n) return;
    int lane = threadIdx.x & 63;
    int grp = lane >> 4;
    int L = lane & 15;
    int ch = L * 8;

    h16x8 rx = *(const h16x8*)&xr[((size_t)v << 7) + ch];
    float4 av0 = *(const float4*)&att[ch];
    float4 av1 = *(const float4*)&att[ch + 4];
    h16x2 a[4] = {{(_Float16)av0.x, (_Float16)av0.y},
                  {(_Float16)av0.z, (_Float16)av0.w},
                  {(_Float16)av1.x, (_Float16)av1.y},
                  {(_Float16)av1.z, (_Float16)av1.w}};
    const h16x8 neg8 = {(_Float16)NEG, (_Float16)NEG, (_Float16)NEG, (_Float16)NEG,
                        (_Float16)NEG, (_Float16)NEG, (_Float16)NEG, (_Float16)NEG};

    int beg = rowptr[v];
    int end = rowptr[v + 1];

    float lrun = 0.f;
    float acc[8] = {0.f, 0.f, 0.f, 0.f, 0.f, 0.f, 0.f, 0.f};

    auto proc = [&](h16x8 hv, bool ok) {
        h16x8 s = hv + rx;
        h16x8 l = __builtin_elementwise_max(s, s * neg8);
        const h16x2* lp = (const h16x2*)&l;
        float part = dot8_h(lp, a);
        part += __shfl_xor(part, 1);      // head = lane pair (16 ch) — ONLY xor 1
        float p = ok ? __expf(part) : 0.f;
        lrun += p;
        const _Float16* hp = (const _Float16*)&hv;
#pragma unroll
        for (int k = 0; k < 8; k++) acc[k] = fmaf(p, (float)hp[k], acc[k]);
    };

    for (int cb = beg; cb < end; cb += 64) {
        int ce = min(end, cb + 64);
        int cidx = (cb + lane < end) ? col[cb + lane] : v;   // coalesced, once
        int e = cb;
        for (; e + 8 <= ce; e += 8) {        // 8 edges: two 4-edge waves in flight
            int u0 = __shfl(cidx, e - cb + grp);
            int u1 = __shfl(cidx, e - cb + 4 + grp);
            h16x8 h0 = *(const h16x8*)&xl[((size_t)u0 << 7) + ch];
            h16x8 h1 = *(const h16x8*)&xl[((size_t)u1 << 7) + ch];
            proc(h0, true);
            proc(h1, true);
        }
        for (; e < ce; e += 4) {             // masked tail, 4-edge granularity
            bool ok = (e + grp < ce);
            int u = __shfl(cidx, e - cb + grp);
            if (!ok) u = v;                  // valid row; p masked to 0
            h16x8 h0 = *(const h16x8*)&xl[((size_t)u << 7) + ch];
            proc(h0, ok);
        }
    }

    // combine the four 16-lane groups (same channels, different edges)
    lrun += __shfl_xor(lrun, 16);
    lrun += __shfl_xor(lrun, 32);
#pragma unroll
    for (int k = 0; k < 8; k++) {
        acc[k] += __shfl_xor(acc[k], 16);
        acc[k] += __shfl_xor(acc[k], 32);
    }

    if (grp == 0) {
        float inv = 1.0f / lrun;
        float4 b0 = *(const float4*)&bias[ch];
        float4 b1 = *(const float4*)&bias[ch + 4];
        float4 m0 = *(const float4*)&bm[ch];
        float4 m1 = *(const float4*)&bm[ch + 4];
        float4 v0 = *(const float4*)&bv[ch];
        float4 v1 = *(const float4*)&bv[ch + 4];
        float4 g0 = *(const float4*)&g[ch];
        float4 g1 = *(const float4*)&g[ch + 4];
        float4 e0 = *(const float4*)&be[ch];
        float4 e1 = *(const float4*)&be[ch + 4];
        float bb[8] = {b0.x, b0.y, b0.z, b0.w, b1.x, b1.y, b1.z, b1.w};
        float ms[8] = {m0.x, m0.y, m0.z, m0.w, m1.x, m1.y, m1.z, m1.w};
        float vs[8] = {v0.x, v0.y, v0.z, v0.w, v1.x, v1.y, v1.z, v1.w};
        float gs[8] = {g0.x, g0.y, g0.z, g0.w, g1.x, g1.y, g1.z, g1.w};
        float es[8] = {e0.x, e0.y, e0.z, e0.w, e1.x, e1.y, e1.z, e1.w};
        h16x8 outv;
#pragma unroll
        for (int k = 0; k < 8; k++) {
            float o = fmaf(acc[k], inv, bb[k]);
            o = (o - ms[k]) * rsqrtf(vs[k] + BN_EPS) * gs[k] + es[k];
            o = o > 0.f ? o : expm1f(o);
            outv[k] = (_Float16)o;
        }
        *(h16x8*)&oh[((size_t)v << 7) + ch] = outv;
    }
}

// ---------------- final aggregate, fp32, HC=16, writes d_out ----------------

__global__ __launch_bounds__(256) void agg_f(
    const float* __restrict__ xl, const float* __restrict__ xr,
    const int* __restrict__ rowptr, const int* __restrict__ col,
    const float* __restrict__ att, const float* __restrict__ bias,
    float* __restrict__ out, int n) {
    int v = (blockIdx.x * blockDim.x + threadIdx.x) >> 6;
    if (v >= n) return;
    int lane = threadIdx.x & 63;
    int slot = lane >> 2;        // 16 edge slots
    int L = lane & 3;
    int ch = 4 * L;

    float4 xrv = *(const float4*)&xr[((size_t)v << 4) + ch];
    float4 av = *(const float4*)&att[ch];
    int beg = rowptr[v];
    int end = rowptr[v + 1];

    float lrun = 0.f;
    float4 acc = make_float4(0.f, 0.f, 0.f, 0.f);

    for (int cb = beg; cb < end; cb += 64) {
        int ce = min(end, cb + 64);
        int cidx = (cb + lane < end) ? col[cb + lane] : v;   // coalesced, once
        for (int e = cb; e < ce; e += 16) {
            bool ok = (e + slot < ce);
            int u = __shfl(cidx, e - cb + slot);
            if (!ok) u = v;
            float4 xv = *(const float4*)&xl[((size_t)u << 4) + ch];
            float s0 = xv.x + xrv.x; s0 = s0 > 0.f ? s0 : NEG * s0;
            float s1 = xv.y + xrv.y; s1 = s1 > 0.f ? s1 : NEG * s1;
            float s2 = xv.z + xrv.z; s2 = s2 > 0.f ? s2 : NEG * s2;
            float s3 = xv.w + xrv.w; s3 = s3 > 0.f ? s3 : NEG * s3;
            float part = fmaf(s0, av.x, fmaf(s1, av.y, fmaf(s2, av.z, s3 * av.w)));
            part += __shfl_xor(part, 1);
            part += __shfl_xor(part, 2);
            float p = ok ? __expf(part) : 0.f;
            lrun += p;
            acc.x = fmaf(p, xv.x, acc.x);
            acc.y = fmaf(p, xv.y, acc.y);
            acc.z = fmaf(p, xv.z, acc.z);
            acc.w = fmaf(p, xv.w, acc.w);
        }
    }

#pragma unroll
    for (int d = 4; d < 64; d <<= 1) {
        lrun += __shfl_xor(lrun, d);
        acc.x += __shfl_xor(acc.x, d);
        acc.y += __shfl_xor(acc.y, d);
        acc.z += __shfl_xor(acc.z, d);
        acc.w += __shfl_xor(acc.w, d);
    }

    if (slot == 0) {
        float inv = 1.0f / lrun;
        float4 b4 = *(const float4*)&bias[ch];
        *(float4*)&out[((size_t)v << 4) + ch] =
            make_float4(fmaf(acc.x, inv, b4.x), fmaf(acc.y, inv, b4.y),
                        fmaf(acc.z, inv, b4.z), fmaf(acc.w, inv, b4.w));
    }
}

// ---------------- launch ----------------

extern "C" void kernel_launch(void* const* d_in, const int* in_sizes, int n_in,
                              void* d_out, int out_size, void* d_ws, size_t ws_size,
                              hipStream_t stream) {
    const float* x = (const float*)d_in[0];
    const int* ei = (const int*)d_in[1];
    const float* Wl[4] = {(const float*)d_in[2], (const float*)d_in[6],
                          (const float*)d_in[10], (const float*)d_in[14]};
    const float* Wr[4] = {(const float*)d_in[3], (const float*)d_in[7],
                          (const float*)d_in[11], (const float*)d_in[15]};
    const float* att[4] = {(const float*)d_in[4], (const float*)d_in[8],
                           (const float*)d_in[12], (const float*)d_in[16]};
    const float* bias[4] = {(const float*)d_in[5], (const float*)d_in[9],
                            (const float*)d_in[13], (const float*)d_in[17]};
    const float* g[3] = {(const float*)d_in[18], (const float*)d_in[22], (const float*)d_in[26]};
    const float* be[3] = {(const float*)d_in[19], (const float*)d_in[23], (const float*)d_in[27]};
    const float* bm[3] = {(const float*)d_in[20], (const float*)d_in[24], (const float*)d_in[28]};
    const float* bv[3] = {(const float*)d_in[21], (const float*)d_in[25], (const float*)d_in[29]};

    const int n = in_sizes[0] / 128;
    const int E = in_sizes[1] / 2;
    const int ET = E + n;

    char* p = (char*)d_ws;
    __half* xh = (__half*)p;           p += (size_t)n * 128 * 2;
    __half* xlh = (__half*)p;          p += (size_t)n * 128 * 2;
    __half* xrh = (__half*)p;          p += (size_t)n * 128 * 2;
    float* xl3 = (float*)p;            p += (size_t)n * 16 * 4;
    float* xr3 = (float*)p;            p += (size_t)n * 16 * 4;
    int* rowptr = (int*)p;            p += (size_t)(n + 4) * 4;   // padded for alignment
    int* cnt = (int*)p;               p += (size_t)n * 4;
    int* fill = (int*)p;              p += (size_t)n * 4;   // contiguous after cnt
    int* col = (int*)p;               p += (size_t)ET * 4;
    int* bsums = (int*)p;             p += 256;
    __half* pk[4];
    for (int i = 0; i < 3; i++) { pk[i] = (__half*)p; p += 4 * 16 * 512 * 2; }
    pk[3] = (__half*)p;               p += 4 * 2 * 512 * 2;

    // one memset over cnt+fill (adjacent, 8n bytes)
    (void)hipMemsetAsync(cnt, 0, (size_t)n * 8, stream);

    const int tb = 256;
    const int histBlocks = (ET + tb - 1) / tb;
    hist_pack<<<200 + histBlocks, tb, 0, stream>>>(
        ei, E, n, cnt,
        Wl[0], Wr[0], Wl[1], Wr[1], Wl[2], Wr[2], Wl[3], Wr[3],
        pk[0], pk[1], pk[2], pk[3]);

    const int nb = (n + 1023) / 1024;
    const int gb64 = (n + 63) / 64;
    const int gemmBlocksSmall = ((n + 15) / 16 + 3) / 4;
    const int aggBlocks = (n + 3) / 4;    // 1 node per wave, 4 waves/block

    // scan_block co-dispatched with layer-0 GEMM (independent work)
    scanblk_gemm0<<<nb + gb64, 256, 0, stream>>>(
        cnt, rowptr, bsums, n, nb, x, pk[0], xlh, xrh);
    scan_add2<<<nb, 1024, 0, stream>>>(rowptr, bsums, n, nb);
    scatter_kernel<<<(ET + tb - 1) / tb, tb, 0, stream>>>(ei, E, n, rowptr, fill, col);

    agg_h<<<aggBlocks, 256, 0, stream>>>(
        xlh, xrh, rowptr, col, att[0], bias[0], g[0], be[0], bm[0], bv[0], xh, n);
    for (int i = 1; i < 3; i++) {
        gemm_h_big2<<<gb64, 256, 0, stream>>>(xh, pk[i], xlh, xrh, n);
        agg_h<<<aggBlocks, 256, 0, stream>>>(
            xlh, xrh, rowptr, col, att[i], bias[i], g[i], be[i], bm[i], bv[i], xh, n);
    }
    gemm_h_small<<<gemmBlocksSmall, 256, 0, stream>>>(xh, pk[3], xl3, xr3, n);
    agg_f<<<aggBlocks, 256, 0, stream>>>(
        xl3, xr3, rowptr, col, att[3], bias[3], (float*)d_out, n);
}

// Round 3
// 369.278 us; speedup vs baseline: 1.0167x; 1.0167x over previous
//
#include <hip/hip_runtime.h>
#include <hip/hip_fp16.h>
#include <math.h>

static constexpr float BN_EPS = 1e-5f;
static constexpr float NEG = 0.2f;

typedef float f32x4 __attribute__((ext_vector_type(4)));
typedef _Float16 h16x2 __attribute__((ext_vector_type(2)));
typedef _Float16 h16x8 __attribute__((ext_vector_type(8)));

// ---------------- hist + W-pack fused (independent work, chain start) --------
// blocks 0..191: pack layers 0-2 (NTT=16, M=128); 192..199: pack layer 3
// (NTT=2, M=16); blocks 200+: dst histogram (self-loop for e >= E).

__global__ __launch_bounds__(256) void hist_pack(
    const int* __restrict__ ei, int E, int n, int* __restrict__ cnt,
    const float* __restrict__ W0l, const float* __restrict__ W0r,
    const float* __restrict__ W1l, const float* __restrict__ W1r,
    const float* __restrict__ W2l, const float* __restrict__ W2r,
    const float* __restrict__ W3l, const float* __restrict__ W3r,
    __half* __restrict__ pk0, __half* __restrict__ pk1,
    __half* __restrict__ pk2, __half* __restrict__ pk3) {
    int b = blockIdx.x;
    if (b < 200) {
        if (threadIdx.x >= 64) return;
        const float *Wl, *Wr;
        __half* packed;
        int tile, NTT, M;
        if (b < 192) {
            int layer = b >> 6;
            tile = b & 63;
            NTT = 16; M = 128;
            Wl = (layer == 0) ? W0l : (layer == 1) ? W1l : W2l;
            Wr = (layer == 0) ? W0r : (layer == 1) ? W1r : W2r;
            packed = (layer == 0) ? pk0 : (layer == 1) ? pk1 : pk2;
        } else {
            tile = b - 192;
            NTT = 2; M = 16;
            Wl = W3l; Wr = W3r; packed = pk3;
        }
        int NT = NTT >> 1;
        int gnt = tile % NTT;
        int kt = tile / NTT;
        int l = threadIdx.x;
        const float* W = (gnt < NT) ? Wl : Wr;
        int col = (gnt % NT) * 16 + (l & 15);
        int krow = kt * 32 + ((l >> 4) << 3);
        size_t base = (size_t)tile * 512 + (size_t)l * 8;
#pragma unroll
        for (int j = 0; j < 8; j++)
            packed[base + j] = __float2half(W[(size_t)(krow + j) * M + col]);
    } else {
        int e = (b - 200) * 256 + threadIdx.x;
        int ET = E + n;
        if (e >= ET) return;
        int d = (e < E) ? ei[E + e] : (e - E);
        atomicAdd(&cnt[d], 1);
    }
}

// ---------------- CSR scan chain (kernel boundaries are the cheap barrier) ---
// 256-thread scan body (4 elements/thread) so it can co-dispatch with the
// layer-0 GEMM without capping the GEMM's VGPR budget.

__device__ __forceinline__ void scan_block_body256(
    const int* __restrict__ cnt, int* __restrict__ rowptr,
    int* __restrict__ bsums, int n, int bid, int* s) {
    int t = threadIdx.x;               // 0..255
    int base = bid * 1024 + t * 4;
    int v0 = 0, v1 = 0, v2 = 0, v3 = 0;
    if (base + 3 < n) {
        v0 = cnt[base];     v1 = cnt[base + 1];
        v2 = cnt[base + 2]; v3 = cnt[base + 3];
    } else {
        if (base < n)     v0 = cnt[base];
        if (base + 1 < n) v1 = cnt[base + 1];
        if (base + 2 < n) v2 = cnt[base + 2];
        if (base + 3 < n) v3 = cnt[base + 3];
    }
    int p1 = v0 + v1, p2 = p1 + v2, p3 = p2 + v3;
    s[t] = p3;
    __syncthreads();
    for (int d = 1; d < 256; d <<= 1) {
        int tt = (t >= d) ? s[t - d] : 0;
        __syncthreads();
        s[t] += tt;
        __syncthreads();
    }
    int ex = s[t] - p3;                // exclusive offset for this thread
    if (base < n)     rowptr[base + 1] = ex + v0;
    if (base + 1 < n) rowptr[base + 2] = ex + p1;
    if (base + 2 < n) rowptr[base + 3] = ex + p2;
    if (base + 3 < n) rowptr[base + 4] = ex + p3;
    if (t == 255) bsums[bid] = s[255];
}

// fused: each block redundantly wave-scans the (raw) per-block sums, picks its
// own exclusive offset, then adds. Replaces scan_bsums + scan_add (nb <= 64).
__global__ __launch_bounds__(1024) void scan_add2(
    int* __restrict__ rowptr, const int* __restrict__ bsums, int n, int nb) {
    __shared__ int sex;
    if (threadIdx.x < 64) {
        int L = threadIdx.x;
        int v = (L < nb) ? bsums[L] : 0;
#pragma unroll
        for (int d = 1; d < 64; d <<= 1) {
            int t = __shfl_up(v, d);
            if (L >= d) v += t;
        }
        int ex = __shfl_up(v, 1);
        if (L == 0) ex = 0;
        if (L == (int)blockIdx.x) sex = ex;
    }
    __syncthreads();
    int i = blockIdx.x * 1024 + threadIdx.x;
    if (i < n) rowptr[i + 1] += sex;
    if (i == 0) rowptr[0] = 0;
}

__global__ void scatter_kernel(const int* __restrict__ ei, int E, int n,
                               const int* __restrict__ rowptr, int* __restrict__ fill,
                               int* __restrict__ col) {
    int e = blockIdx.x * blockDim.x + threadIdx.x;
    int ET = E + n;
    if (e >= ET) return;
    int s, d;
    if (e < E) { s = ei[e]; d = ei[E + e]; } else { s = e - E; d = s; }
    int pos = atomicAdd(&fill[d], 1);
    col[rowptr[d] + pos] = s;
}

// ---------------- fp16 MFMA dual GEMM: Y1 = X@Wl, Y2 = X@Wr (M=128 each) ----
// body as a device fn so layer 0 can co-dispatch with scan_block.

template <bool FIRST>
__device__ __forceinline__ void gemm_body(
    const __half* __restrict__ xh, const float* __restrict__ xf,
    const __half* __restrict__ packed,
    __half* __restrict__ Y1, __half* __restrict__ Y2, int n, int bid,
    _Float16* sA) {
    const int t = threadIdx.x;
    const int row0 = bid * 64;

    for (int c = t; c < 1024; c += 256) {
        int row = c >> 4;
        int off = (c & 15) * 8;
        int gr = row0 + row;
        if (gr >= n) gr = n - 1;
        if (FIRST) {
            float4 v0 = *(const float4*)&xf[(size_t)gr * 128 + off];
            float4 v1 = *(const float4*)&xf[(size_t)gr * 128 + off + 4];
            h16x8 h = {(_Float16)v0.x, (_Float16)v0.y, (_Float16)v0.z, (_Float16)v0.w,
                       (_Float16)v1.x, (_Float16)v1.y, (_Float16)v1.z, (_Float16)v1.w};
            *(h16x8*)&sA[row * 136 + off] = h;
        } else {
            *(h16x8*)&sA[row * 136 + off] = *(const h16x8*)&xh[(size_t)gr * 128 + off];
        }
    }
    __syncthreads();

    const int lane = t & 63;
    const int s = t >> 6;
    const int lr = lane & 15;
    const int kq = (lane >> 4) * 8;

    h16x8 af[4][4];                 // [rt][kt]
#pragma unroll
    for (int rt = 0; rt < 4; rt++)
#pragma unroll
        for (int kt = 0; kt < 4; kt++)
            af[rt][kt] = *(const h16x8*)&sA[(rt * 16 + lr) * 136 + kt * 32 + kq];

    f32x4 acc[4][4];                // [ntl][rt]
#pragma unroll
    for (int a = 0; a < 4; a++)
#pragma unroll
        for (int b = 0; b < 4; b++) acc[a][b] = (f32x4){0.f, 0.f, 0.f, 0.f};

#pragma unroll
    for (int kt = 0; kt < 4; kt++) {
#pragma unroll
        for (int ntl = 0; ntl < 4; ntl++) {
            int nt = s * 4 + ntl;
            h16x8 b = *(const h16x8*)&packed[((size_t)(kt * 16 + nt)) * 512 + lane * 8];
#pragma unroll
            for (int rt = 0; rt < 4; rt++)
                acc[ntl][rt] = __builtin_amdgcn_mfma_f32_16x16x32_f16(af[rt][kt], b, acc[ntl][rt], 0, 0, 0);
        }
    }

    __half* Y = (s < 2) ? Y1 : Y2;
    const int colh = (s & 1) * 64;
    const int rq = (lane >> 4) * 4;
#pragma unroll
    for (int ntl = 0; ntl < 4; ntl++) {
        int col = colh + ntl * 16 + lr;
#pragma unroll
        for (int rt = 0; rt < 4; rt++) {
#pragma unroll
            for (int g = 0; g < 4; g++) {
                int row = row0 + rt * 16 + rq + g;
                if (row < n) Y[(size_t)row * 128 + col] = __float2half(acc[ntl][rt][g]);
            }
        }
    }
}

__global__ __launch_bounds__(256) void gemm_h_big2(
    const __half* __restrict__ xh, const __half* __restrict__ packed,
    __half* __restrict__ Y1, __half* __restrict__ Y2, int n) {
    __shared__ __align__(16) char smem[64 * 136 * 2];
    gemm_body<false>(xh, nullptr, packed, Y1, Y2, n, blockIdx.x, (_Float16*)smem);
}

// fused dispatch: blocks [0, nscan) do the CSR block-scan, the rest run the
// layer-0 GEMM (both depend only on hist_pack; independent of each other).
__global__ __launch_bounds__(256) void scanblk_gemm0(
    const int* __restrict__ cnt, int* __restrict__ rowptr,
    int* __restrict__ bsums, int n, int nscan,
    const float* __restrict__ xf, const __half* __restrict__ packed,
    __half* __restrict__ Y1, __half* __restrict__ Y2) {
    __shared__ __align__(16) char smem[64 * 136 * 2];
    int b = blockIdx.x;
    if (b < nscan) {
        scan_block_body256(cnt, rowptr, bsums, n, b, (int*)smem);
    } else {
        gemm_body<true>(nullptr, xf, packed, Y1, Y2, n, b - nscan,
                        (_Float16*)smem);
    }
}

// ---------------- small fp16 GEMM for layer 3 (M=16 each, fp32 out) ----------

__global__ __launch_bounds__(256) void gemm_h_small(
    const __half* __restrict__ xh, const __half* __restrict__ packed,
    float* __restrict__ Y1, float* __restrict__ Y2, int n) {
    int lane = threadIdx.x & 63;
    int wv = blockIdx.x * 4 + (threadIdx.x >> 6);
    int row0 = wv * 16;
    if (row0 >= n) return;
    int r = row0 + (lane & 15);
    if (r >= n) r = n - 1;
    int kq = (lane >> 4) * 8;

    h16x8 af[4];
#pragma unroll
    for (int kt = 0; kt < 4; kt++)
        af[kt] = *(const h16x8*)&xh[(size_t)r * 128 + kt * 32 + kq];

    f32x4 acc[2];
    acc[0] = (f32x4){0.f, 0.f, 0.f, 0.f};
    acc[1] = (f32x4){0.f, 0.f, 0.f, 0.f};

#pragma unroll
    for (int kt = 0; kt < 4; kt++) {
#pragma unroll
        for (int nt = 0; nt < 2; nt++) {
            h16x8 b = *(const h16x8*)&packed[((size_t)(kt * 2 + nt)) * 512 + lane * 8];
            acc[nt] = __builtin_amdgcn_mfma_f32_16x16x32_f16(af[kt], b, acc[nt], 0, 0, 0);
        }
    }

    int colb = lane & 15;
    int rbase = row0 + (lane >> 4) * 4;
#pragma unroll
    for (int nt = 0; nt < 2; nt++) {
        float* Y = (nt == 0) ? Y1 : Y2;
#pragma unroll
        for (int g = 0; g < 4; g++) {
            int row = rbase + g;
            if (row < n) Y[(size_t)row * 16 + colb] = acc[nt][g];
        }
    }
}

// ---------------- Fused GATv2 aggregate (uniform 16-slot batches) -----------
// Wave = one node. 4 groups x 16 lanes; per 16-slot batch each group issues 4
// gathers back-to-back (4 edges in flight), lane owns 8 channels (16B gather).
// Head (C=16) = a lane PAIR -> per-head logit reduce is shfl_xor(1) only.
// col window (64 edges) loaded coalesced BEFORE setup loads so its latency
// overlaps; out-of-range slots read lane-default v (self) and mask p to 0.
// Epilogue: after xor16/32 combine the 8-ch accumulator is replicated in all
// 4 groups -> group g finalizes channels {2g, 2g+1}: all 64 lanes active,
// store is one contiguous 256B wave store.

__device__ __forceinline__ float dot8_h(const h16x2* lp, const h16x2* ap) {
#if __has_builtin(__builtin_amdgcn_fdot2)
    float part = __builtin_amdgcn_fdot2(lp[0], ap[0], 0.f, false);
    part = __builtin_amdgcn_fdot2(lp[1], ap[1], part, false);
    part = __builtin_amdgcn_fdot2(lp[2], ap[2], part, false);
    return __builtin_amdgcn_fdot2(lp[3], ap[3], part, false);
#else
    float part = 0.f;
#pragma unroll
    for (int i = 0; i < 4; i++)
        part += (float)lp[i].x * (float)ap[i].x + (float)lp[i].y * (float)ap[i].y;
    return part;
#endif
}

__global__ __launch_bounds__(256) void agg_h(
    const __half* __restrict__ xl, const __half* __restrict__ xr,
    const int* __restrict__ rowptr, const int* __restrict__ col,
    const float* __restrict__ att, const float* __restrict__ bias,
    const float* __restrict__ g, const float* __restrict__ be,
    const float* __restrict__ bm, const float* __restrict__ bv,
    __half* __restrict__ oh, int n) {
    int v = (blockIdx.x * blockDim.x + threadIdx.x) >> 6;
    if (v >= n) return;
    int lane = threadIdx.x & 63;
    int grp = lane >> 4;
    int L = lane & 15;
    int ch = L * 8;

    int beg = rowptr[v];
    int end = rowptr[v + 1];
    // first col window: issue BEFORE setup loads (latency overlap)
    int cb = beg;
    int cidx = (cb + lane < end) ? col[cb + lane] : v;

    h16x8 rx = *(const h16x8*)&xr[((size_t)v << 7) + ch];
    float4 av0 = *(const float4*)&att[ch];
    float4 av1 = *(const float4*)&att[ch + 4];
    h16x2 a[4] = {{(_Float16)av0.x, (_Float16)av0.y},
                  {(_Float16)av0.z, (_Float16)av0.w},
                  {(_Float16)av1.x, (_Float16)av1.y},
                  {(_Float16)av1.z, (_Float16)av1.w}};
    const h16x8 neg8 = {(_Float16)NEG, (_Float16)NEG, (_Float16)NEG, (_Float16)NEG,
                        (_Float16)NEG, (_Float16)NEG, (_Float16)NEG, (_Float16)NEG};

    float lrun = 0.f;
    float acc[8] = {0.f, 0.f, 0.f, 0.f, 0.f, 0.f, 0.f, 0.f};

    auto proc = [&](h16x8 hv, bool ok) {
        h16x8 s = hv + rx;
        h16x8 l = __builtin_elementwise_max(s, s * neg8);
        const h16x2* lp = (const h16x2*)&l;
        float part = dot8_h(lp, a);
        part += __shfl_xor(part, 1);      // head = lane pair (16 ch)
        float p = ok ? __expf(part) : 0.f;
        lrun += p;
        const _Float16* hp = (const _Float16*)&hv;
#pragma unroll
        for (int k = 0; k < 8; k++) acc[k] = fmaf(p, (float)hp[k], acc[k]);
    };

    while (true) {
        int ce = min(end, cb + 64);
        for (int e = cb; e < ce; e += 16) {   // 16 slots: 4 edges/grp in flight
            int off = e - cb;
            h16x8 hv[4];
#pragma unroll
            for (int j = 0; j < 4; j++) {
                int u = __shfl(cidx, off + 4 * j + grp);  // masked slots -> v
                hv[j] = *(const h16x8*)&xl[((size_t)u << 7) + ch];
            }
#pragma unroll
            for (int j = 0; j < 4; j++) proc(hv[j], e + 4 * j + grp < ce);
        }
        cb += 64;
        if (cb >= end) break;
        cidx = (cb + lane < end) ? col[cb + lane] : v;
    }

    // combine the four 16-lane groups (same channels, different edges)
    lrun += __shfl_xor(lrun, 16);
    lrun += __shfl_xor(lrun, 32);
#pragma unroll
    for (int k = 0; k < 8; k++) {
        acc[k] += __shfl_xor(acc[k], 16);
        acc[k] += __shfl_xor(acc[k], 32);
    }

    // epilogue: group g owns channels {2g, 2g+1} of this lane's octet
    float inv = 1.0f / lrun;
    int c2 = ch + 2 * grp;
    float2 b2 = *(const float2*)&bias[c2];
    float2 m2 = *(const float2*)&bm[c2];
    float2 v2 = *(const float2*)&bv[c2];
    float2 g2 = *(const float2*)&g[c2];
    float2 e2 = *(const float2*)&be[c2];
    float bbv[2] = {b2.x, b2.y}, msv[2] = {m2.x, m2.y}, vsv[2] = {v2.x, v2.y};
    float gsv[2] = {g2.x, g2.y}, esv[2] = {e2.x, e2.y};
    unsigned short hs[2];
#pragma unroll
    for (int j = 0; j < 2; j++) {
        float o = fmaf(acc[2 * grp + j], inv, bbv[j]);
        o = (o - msv[j]) * rsqrtf(vsv[j] + BN_EPS) * gsv[j] + esv[j];
        o = o > 0.f ? o : expm1f(o);
        hs[j] = __half_as_ushort(__float2half(o));
    }
    *(ushort2*)&oh[((size_t)v << 7) + c2] = make_ushort2(hs[0], hs[1]);
}

// ---------------- final aggregate, fp32, HC=16, writes d_out ----------------

__global__ __launch_bounds__(256) void agg_f(
    const float* __restrict__ xl, const float* __restrict__ xr,
    const int* __restrict__ rowptr, const int* __restrict__ col,
    const float* __restrict__ att, const float* __restrict__ bias,
    float* __restrict__ out, int n) {
    int v = (blockIdx.x * blockDim.x + threadIdx.x) >> 6;
    if (v >= n) return;
    int lane = threadIdx.x & 63;
    int slot = lane >> 2;        // 16 edge slots
    int L = lane & 3;
    int ch = 4 * L;

    int beg = rowptr[v];
    int end = rowptr[v + 1];
    int cb = beg;
    int cidx = (cb + lane < end) ? col[cb + lane] : v;   // before setup loads

    float4 xrv = *(const float4*)&xr[((size_t)v << 4) + ch];
    float4 av = *(const float4*)&att[ch];

    float lrun = 0.f;
    float4 acc = make_float4(0.f, 0.f, 0.f, 0.f);

    while (true) {
        int ce = min(end, cb + 64);
        for (int e = cb; e < ce; e += 16) {
            bool ok = (e + slot < ce);
            int u = __shfl(cidx, e - cb + slot);
            float4 xv = *(const float4*)&xl[((size_t)u << 4) + ch];
            float s0 = xv.x + xrv.x; s0 = s0 > 0.f ? s0 : NEG * s0;
            float s1 = xv.y + xrv.y; s1 = s1 > 0.f ? s1 : NEG * s1;
            float s2 = xv.z + xrv.z; s2 = s2 > 0.f ? s2 : NEG * s2;
            float s3 = xv.w + xrv.w; s3 = s3 > 0.f ? s3 : NEG * s3;
            float part = fmaf(s0, av.x, fmaf(s1, av.y, fmaf(s2, av.z, s3 * av.w)));
            part += __shfl_xor(part, 1);
            part += __shfl_xor(part, 2);
            float p = ok ? __expf(part) : 0.f;
            lrun += p;
            acc.x = fmaf(p, xv.x, acc.x);
            acc.y = fmaf(p, xv.y, acc.y);
            acc.z = fmaf(p, xv.z, acc.z);
            acc.w = fmaf(p, xv.w, acc.w);
        }
        cb += 64;
        if (cb >= end) break;
        cidx = (cb + lane < end) ? col[cb + lane] : v;
    }

#pragma unroll
    for (int d = 4; d < 64; d <<= 1) {
        lrun += __shfl_xor(lrun, d);
        acc.x += __shfl_xor(acc.x, d);
        acc.y += __shfl_xor(acc.y, d);
        acc.z += __shfl_xor(acc.z, d);
        acc.w += __shfl_xor(acc.w, d);
    }

    if (slot == 0) {
        float inv = 1.0f / lrun;
        float4 b4 = *(const float4*)&bias[ch];
        *(float4*)&out[((size_t)v << 4) + ch] =
            make_float4(fmaf(acc.x, inv, b4.x), fmaf(acc.y, inv, b4.y),
                        fmaf(acc.z, inv, b4.z), fmaf(acc.w, inv, b4.w));
    }
}

// ---------------- launch ----------------

extern "C" void kernel_launch(void* const* d_in, const int* in_sizes, int n_in,
                              void* d_out, int out_size, void* d_ws, size_t ws_size,
                              hipStream_t stream) {
    const float* x = (const float*)d_in[0];
    const int* ei = (const int*)d_in[1];
    const float* Wl[4] = {(const float*)d_in[2], (const float*)d_in[6],
                          (const float*)d_in[10], (const float*)d_in[14]};
    const float* Wr[4] = {(const float*)d_in[3], (const float*)d_in[7],
                          (const float*)d_in[11], (const float*)d_in[15]};
    const float* att[4] = {(const float*)d_in[4], (const float*)d_in[8],
                           (const float*)d_in[12], (const float*)d_in[16]};
    const float* bias[4] = {(const float*)d_in[5], (const float*)d_in[9],
                            (const float*)d_in[13], (const float*)d_in[17]};
    const float* g[3] = {(const float*)d_in[18], (const float*)d_in[22], (const float*)d_in[26]};
    const float* be[3] = {(const float*)d_in[19], (const float*)d_in[23], (const float*)d_in[27]};
    const float* bm[3] = {(const float*)d_in[20], (const float*)d_in[24], (const float*)d_in[28]};
    const float* bv[3] = {(const float*)d_in[21], (const float*)d_in[25], (const float*)d_in[29]};

    const int n = in_sizes[0] / 128;
    const int E = in_sizes[1] / 2;
    const int ET = E + n;

    char* p = (char*)d_ws;
    __half* xh = (__half*)p;           p += (size_t)n * 128 * 2;
    __half* xlh = (__half*)p;          p += (size_t)n * 128 * 2;
    __half* xrh = (__half*)p;          p += (size_t)n * 128 * 2;
    float* xl3 = (float*)p;            p += (size_t)n * 16 * 4;
    float* xr3 = (float*)p;            p += (size_t)n * 16 * 4;
    int* rowptr = (int*)p;            p += (size_t)(n + 4) * 4;   // padded for alignment
    int* cnt = (int*)p;               p += (size_t)n * 4;
    int* fill = (int*)p;              p += (size_t)n * 4;   // contiguous after cnt
    int* col = (int*)p;               p += (size_t)ET * 4;
    int* bsums = (int*)p;             p += 256;
    __half* pk[4];
    for (int i = 0; i < 3; i++) { pk[i] = (__half*)p; p += 4 * 16 * 512 * 2; }
    pk[3] = (__half*)p;               p += 4 * 2 * 512 * 2;

    // one memset over cnt+fill (adjacent, 8n bytes)
    (void)hipMemsetAsync(cnt, 0, (size_t)n * 8, stream);

    const int tb = 256;
    const int histBlocks = (ET + tb - 1) / tb;
    hist_pack<<<200 + histBlocks, tb, 0, stream>>>(
        ei, E, n, cnt,
        Wl[0], Wr[0], Wl[1], Wr[1], Wl[2], Wr[2], Wl[3], Wr[3],
        pk[0], pk[1], pk[2], pk[3]);

    const int nb = (n + 1023) / 1024;
    const int gb64 = (n + 63) / 64;
    const int gemmBlocksSmall = ((n + 15) / 16 + 3) / 4;
    const int aggBlocks = (n + 3) / 4;    // 1 node per wave, 4 waves/block

    // scan_block co-dispatched with layer-0 GEMM (independent work)
    scanblk_gemm0<<<nb + gb64, 256, 0, stream>>>(
        cnt, rowptr, bsums, n, nb, x, pk[0], xlh, xrh);
    scan_add2<<<nb, 1024, 0, stream>>>(rowptr, bsums, n, nb);
    scatter_kernel<<<(ET + tb - 1) / tb, tb, 0, stream>>>(ei, E, n, rowptr, fill, col);

    agg_h<<<aggBlocks, 256, 0, stream>>>(
        xlh, xrh, rowptr, col, att[0], bias[0], g[0], be[0], bm[0], bv[0], xh, n);
    for (int i = 1; i < 3; i++) {
        gemm_h_big2<<<gb64, 256, 0, stream>>>(xh, pk[i], xlh, xrh, n);
        agg_h<<<aggBlocks, 256, 0, stream>>>(
            xlh, xrh, rowptr, col, att[i], bias[i], g[i], be[i], bm[i], bv[i], xh, n);
    }
    gemm_h_small<<<gemmBlocksSmall, 256, 0, stream>>>(xh, pk[3], xl3, xr3, n);
    agg_f<<<aggBlocks, 256, 0, stream>>>(
        xl3, xr3, rowptr, col, att[3], bias[3], (float*)d_out, n);
}

// Round 4
// 329.640 us; speedup vs baseline: 1.1389x; 1.1202x over previous
//
#include <hip/hip_runtime.h>
#include <hip/hip_fp16.h>
#include <math.h>

static constexpr float BN_EPS = 1e-5f;
static constexpr float NEG = 0.2f;

typedef float f32x4 __attribute__((ext_vector_type(4)));
typedef _Float16 h16x2 __attribute__((ext_vector_type(2)));
typedef _Float16 h16x8 __attribute__((ext_vector_type(8)));

// ---------------- hist + W-pack + BN-fold fused (chain start) ---------------
// blocks 0..191: pack layers 0-2 (NTT=16, M=128); 192..199: pack layer 3
// (NTT=2, M=16); block 200: BN fold (A = g*rsqrt(v+eps), B = (bias-m)*A+be);
// blocks 201+: dst histogram (self-loop for e >= E).

__global__ __launch_bounds__(256) void hist_pack(
    const int* __restrict__ ei, int E, int n, int* __restrict__ cnt,
    const float* __restrict__ W0l, const float* __restrict__ W0r,
    const float* __restrict__ W1l, const float* __restrict__ W1r,
    const float* __restrict__ W2l, const float* __restrict__ W2r,
    const float* __restrict__ W3l, const float* __restrict__ W3r,
    __half* __restrict__ pk0, __half* __restrict__ pk1,
    __half* __restrict__ pk2, __half* __restrict__ pk3,
    const float* __restrict__ b0, const float* __restrict__ b1,
    const float* __restrict__ b2,
    const float* __restrict__ g0, const float* __restrict__ g1,
    const float* __restrict__ g2,
    const float* __restrict__ be0, const float* __restrict__ be1,
    const float* __restrict__ be2,
    const float* __restrict__ m0, const float* __restrict__ m1,
    const float* __restrict__ m2,
    const float* __restrict__ v0, const float* __restrict__ v1,
    const float* __restrict__ v2,
    float* __restrict__ bnA, float* __restrict__ bnB) {
    int b = blockIdx.x;
    if (b < 200) {
        if (threadIdx.x >= 64) return;
        const float *Wl, *Wr;
        __half* packed;
        int tile, NTT, M;
        if (b < 192) {
            int layer = b >> 6;
            tile = b & 63;
            NTT = 16; M = 128;
            Wl = (layer == 0) ? W0l : (layer == 1) ? W1l : W2l;
            Wr = (layer == 0) ? W0r : (layer == 1) ? W1r : W2r;
            packed = (layer == 0) ? pk0 : (layer == 1) ? pk1 : pk2;
        } else {
            tile = b - 192;
            NTT = 2; M = 16;
            Wl = W3l; Wr = W3r; packed = pk3;
        }
        int NT = NTT >> 1;
        int gnt = tile % NTT;
        int kt = tile / NTT;
        int l = threadIdx.x;
        const float* W = (gnt < NT) ? Wl : Wr;
        int col = (gnt % NT) * 16 + (l & 15);
        int krow = kt * 32 + ((l >> 4) << 3);
        size_t base = (size_t)tile * 512 + (size_t)l * 8;
#pragma unroll
        for (int j = 0; j < 8; j++)
            packed[base + j] = __float2half(W[(size_t)(krow + j) * M + col]);
    } else if (b == 200) {
        for (int t = threadIdx.x; t < 384; t += 256) {
            int layer = t >> 7;
            int c = t & 127;
            const float* gg = (layer == 0) ? g0 : (layer == 1) ? g1 : g2;
            const float* ee = (layer == 0) ? be0 : (layer == 1) ? be1 : be2;
            const float* mm = (layer == 0) ? m0 : (layer == 1) ? m1 : m2;
            const float* vv = (layer == 0) ? v0 : (layer == 1) ? v1 : v2;
            const float* bb = (layer == 0) ? b0 : (layer == 1) ? b1 : b2;
            float A = gg[c] * rsqrtf(vv[c] + BN_EPS);
            bnA[t] = A;
            bnB[t] = fmaf(bb[c] - mm[c], A, ee[c]);
        }
    } else {
        int e = (b - 201) * 256 + threadIdx.x;
        int ET = E + n;
        if (e >= ET) return;
        int d = (e < E) ? ei[E + e] : (e - E);
        atomicAdd(&cnt[d], 1);
    }
}

// ---------------- CSR scan chain (kernel boundaries are the cheap barrier) ---
// 256-thread scan body (4 elements/thread) so it can co-dispatch with the
// layer-0 GEMM without capping the GEMM's VGPR budget.

__device__ __forceinline__ void scan_block_body256(
    const int* __restrict__ cnt, int* __restrict__ rowptr,
    int* __restrict__ bsums, int n, int bid, int* s) {
    int t = threadIdx.x;               // 0..255
    int base = bid * 1024 + t * 4;
    int v0 = 0, v1 = 0, v2 = 0, v3 = 0;
    if (base + 3 < n) {
        v0 = cnt[base];     v1 = cnt[base + 1];
        v2 = cnt[base + 2]; v3 = cnt[base + 3];
    } else {
        if (base < n)     v0 = cnt[base];
        if (base + 1 < n) v1 = cnt[base + 1];
        if (base + 2 < n) v2 = cnt[base + 2];
        if (base + 3 < n) v3 = cnt[base + 3];
    }
    int p1 = v0 + v1, p2 = p1 + v2, p3 = p2 + v3;
    s[t] = p3;
    __syncthreads();
    for (int d = 1; d < 256; d <<= 1) {
        int tt = (t >= d) ? s[t - d] : 0;
        __syncthreads();
        s[t] += tt;
        __syncthreads();
    }
    int ex = s[t] - p3;                // exclusive offset for this thread
    if (base < n)     rowptr[base + 1] = ex + v0;
    if (base + 1 < n) rowptr[base + 2] = ex + p1;
    if (base + 2 < n) rowptr[base + 3] = ex + p2;
    if (base + 3 < n) rowptr[base + 4] = ex + p3;
    if (t == 255) bsums[bid] = s[255];
}

// fused: each block redundantly wave-scans the (raw) per-block sums, picks its
// own exclusive offset, then adds. Replaces scan_bsums + scan_add (nb <= 64).
__global__ __launch_bounds__(1024) void scan_add2(
    int* __restrict__ rowptr, const int* __restrict__ bsums, int n, int nb) {
    __shared__ int sex;
    if (threadIdx.x < 64) {
        int L = threadIdx.x;
        int v = (L < nb) ? bsums[L] : 0;
#pragma unroll
        for (int d = 1; d < 64; d <<= 1) {
            int t = __shfl_up(v, d);
            if (L >= d) v += t;
        }
        int ex = __shfl_up(v, 1);
        if (L == 0) ex = 0;
        if (L == (int)blockIdx.x) sex = ex;
    }
    __syncthreads();
    int i = blockIdx.x * 1024 + threadIdx.x;
    if (i < n) rowptr[i + 1] += sex;
    if (i == 0) rowptr[0] = 0;
}

__global__ void scatter_kernel(const int* __restrict__ ei, int E, int n,
                               const int* __restrict__ rowptr, int* __restrict__ fill,
                               int* __restrict__ col) {
    int e = blockIdx.x * blockDim.x + threadIdx.x;
    int ET = E + n;
    if (e >= ET) return;
    int s, d;
    if (e < E) { s = ei[e]; d = ei[E + e]; } else { s = e - E; d = s; }
    int pos = atomicAdd(&fill[d], 1);
    col[rowptr[d] + pos] = s;
}

// ---------------- fp16 MFMA dual GEMM: Y1 = X@Wl, Y2 = X@Wr (M=128 each) ----
// body as a device fn so layer 0 can co-dispatch with scan_block.

template <bool FIRST>
__device__ __forceinline__ void gemm_body(
    const __half* __restrict__ xh, const float* __restrict__ xf,
    const __half* __restrict__ packed,
    __half* __restrict__ Y1, __half* __restrict__ Y2, int n, int bid,
    _Float16* sA) {
    const int t = threadIdx.x;
    const int row0 = bid * 64;

    for (int c = t; c < 1024; c += 256) {
        int row = c >> 4;
        int off = (c & 15) * 8;
        int gr = row0 + row;
        if (gr >= n) gr = n - 1;
        if (FIRST) {
            float4 v0 = *(const float4*)&xf[(size_t)gr * 128 + off];
            float4 v1 = *(const float4*)&xf[(size_t)gr * 128 + off + 4];
            h16x8 h = {(_Float16)v0.x, (_Float16)v0.y, (_Float16)v0.z, (_Float16)v0.w,
                       (_Float16)v1.x, (_Float16)v1.y, (_Float16)v1.z, (_Float16)v1.w};
            *(h16x8*)&sA[row * 136 + off] = h;
        } else {
            *(h16x8*)&sA[row * 136 + off] = *(const h16x8*)&xh[(size_t)gr * 128 + off];
        }
    }
    __syncthreads();

    const int lane = t & 63;
    const int s = t >> 6;
    const int lr = lane & 15;
    const int kq = (lane >> 4) * 8;

    h16x8 af[4][4];                 // [rt][kt]
#pragma unroll
    for (int rt = 0; rt < 4; rt++)
#pragma unroll
        for (int kt = 0; kt < 4; kt++)
            af[rt][kt] = *(const h16x8*)&sA[(rt * 16 + lr) * 136 + kt * 32 + kq];

    f32x4 acc[4][4];                // [ntl][rt]
#pragma unroll
    for (int a = 0; a < 4; a++)
#pragma unroll
        for (int b = 0; b < 4; b++) acc[a][b] = (f32x4){0.f, 0.f, 0.f, 0.f};

#pragma unroll
    for (int kt = 0; kt < 4; kt++) {
#pragma unroll
        for (int ntl = 0; ntl < 4; ntl++) {
            int nt = s * 4 + ntl;
            h16x8 b = *(const h16x8*)&packed[((size_t)(kt * 16 + nt)) * 512 + lane * 8];
#pragma unroll
            for (int rt = 0; rt < 4; rt++)
                acc[ntl][rt] = __builtin_amdgcn_mfma_f32_16x16x32_f16(af[rt][kt], b, acc[ntl][rt], 0, 0, 0);
        }
    }

    __half* Y = (s < 2) ? Y1 : Y2;
    const int colh = (s & 1) * 64;
    const int rq = (lane >> 4) * 4;
#pragma unroll
    for (int ntl = 0; ntl < 4; ntl++) {
        int col = colh + ntl * 16 + lr;
#pragma unroll
        for (int rt = 0; rt < 4; rt++) {
#pragma unroll
            for (int g = 0; g < 4; g++) {
                int row = row0 + rt * 16 + rq + g;
                if (row < n) Y[(size_t)row * 128 + col] = __float2half(acc[ntl][rt][g]);
            }
        }
    }
}

__global__ __launch_bounds__(256) void gemm_h_big2(
    const __half* __restrict__ xh, const __half* __restrict__ packed,
    __half* __restrict__ Y1, __half* __restrict__ Y2, int n) {
    __shared__ __align__(16) char smem[64 * 136 * 2];
    gemm_body<false>(xh, nullptr, packed, Y1, Y2, n, blockIdx.x, (_Float16*)smem);
}

// fused dispatch: blocks [0, nscan) do the CSR block-scan, the rest run the
// layer-0 GEMM (both depend only on hist_pack; independent of each other).
__global__ __launch_bounds__(256) void scanblk_gemm0(
    const int* __restrict__ cnt, int* __restrict__ rowptr,
    int* __restrict__ bsums, int n, int nscan,
    const float* __restrict__ xf, const __half* __restrict__ packed,
    __half* __restrict__ Y1, __half* __restrict__ Y2) {
    __shared__ __align__(16) char smem[64 * 136 * 2];
    int b = blockIdx.x;
    if (b < nscan) {
        scan_block_body256(cnt, rowptr, bsums, n, b, (int*)smem);
    } else {
        gemm_body<true>(nullptr, xf, packed, Y1, Y2, n, b - nscan,
                        (_Float16*)smem);
    }
}

// ---------------- small fp16 GEMM for layer 3 (M=16 each, fp32 out) ----------

__global__ __launch_bounds__(256) void gemm_h_small(
    const __half* __restrict__ xh, const __half* __restrict__ packed,
    float* __restrict__ Y1, float* __restrict__ Y2, int n) {
    int lane = threadIdx.x & 63;
    int wv = blockIdx.x * 4 + (threadIdx.x >> 6);
    int row0 = wv * 16;
    if (row0 >= n) return;
    int r = row0 + (lane & 15);
    if (r >= n) r = n - 1;
    int kq = (lane >> 4) * 8;

    h16x8 af[4];
#pragma unroll
    for (int kt = 0; kt < 4; kt++)
        af[kt] = *(const h16x8*)&xh[(size_t)r * 128 + kt * 32 + kq];

    f32x4 acc[2];
    acc[0] = (f32x4){0.f, 0.f, 0.f, 0.f};
    acc[1] = (f32x4){0.f, 0.f, 0.f, 0.f};

#pragma unroll
    for (int kt = 0; kt < 4; kt++) {
#pragma unroll
        for (int nt = 0; nt < 2; nt++) {
            h16x8 b = *(const h16x8*)&packed[((size_t)(kt * 2 + nt)) * 512 + lane * 8];
            acc[nt] = __builtin_amdgcn_mfma_f32_16x16x32_f16(af[kt], b, acc[nt], 0, 0, 0);
        }
    }

    int colb = lane & 15;
    int rbase = row0 + (lane >> 4) * 4;
#pragma unroll
    for (int nt = 0; nt < 2; nt++) {
        float* Y = (nt == 0) ? Y1 : Y2;
#pragma unroll
        for (int g = 0; g < 4; g++) {
            int row = rbase + g;
            if (row < n) Y[(size_t)row * 16 + colb] = acc[nt][g];
        }
    }
}

// ---------------- Fused GATv2 aggregate (16-lane group = node) --------------
// 16 groups/block, 4 nodes/wave. Lane owns 8 channels (16B gather); group
// holds all 128 ch -> no cross-group combine, denominators complete in-group.
// Head (C=16) = a lane PAIR -> per-head logit reduce is shfl_xor(1, same pair).
// Edges serial per group, unrolled x4 -> 16 gathers in flight per wave.
// col window (16 edges) hoisted coalesced; masked slots read self (valid), p=0.
// Epilogue: BN pre-folded to per-channel affine (bnA, bnB): o=fma(acc,inv*A,B).

__device__ __forceinline__ float dot8_h(const h16x2* lp, const h16x2* ap) {
#if __has_builtin(__builtin_amdgcn_fdot2)
    float part = __builtin_amdgcn_fdot2(lp[0], ap[0], 0.f, false);
    part = __builtin_amdgcn_fdot2(lp[1], ap[1], part, false);
    part = __builtin_amdgcn_fdot2(lp[2], ap[2], part, false);
    return __builtin_amdgcn_fdot2(lp[3], ap[3], part, false);
#else
    float part = 0.f;
#pragma unroll
    for (int i = 0; i < 4; i++)
        part += (float)lp[i].x * (float)ap[i].x + (float)lp[i].y * (float)ap[i].y;
    return part;
#endif
}

__global__ __launch_bounds__(256) void agg_h(
    const __half* __restrict__ xl, const __half* __restrict__ xr,
    const int* __restrict__ rowptr, const int* __restrict__ col,
    const float* __restrict__ att,
    const float* __restrict__ bnA, const float* __restrict__ bnB,
    __half* __restrict__ oh, int n) {
    int v = (blockIdx.x * blockDim.x + threadIdx.x) >> 4;   // node per 16-lane group
    if (v >= n) return;
    int L = threadIdx.x & 15;
    int ch = L * 8;

    int beg = rowptr[v];
    int end = rowptr[v + 1];
    int cb = beg;
    int cidx = (cb + L < end) ? col[cb + L] : v;   // 16-edge window, coalesced

    h16x8 rx = *(const h16x8*)&xr[((size_t)v << 7) + ch];
    float4 av0 = *(const float4*)&att[ch];
    float4 av1 = *(const float4*)&att[ch + 4];
    h16x2 a[4] = {{(_Float16)av0.x, (_Float16)av0.y},
                  {(_Float16)av0.z, (_Float16)av0.w},
                  {(_Float16)av1.x, (_Float16)av1.y},
                  {(_Float16)av1.z, (_Float16)av1.w}};
    const h16x8 neg8 = {(_Float16)NEG, (_Float16)NEG, (_Float16)NEG, (_Float16)NEG,
                        (_Float16)NEG, (_Float16)NEG, (_Float16)NEG, (_Float16)NEG};

    float lrun = 0.f;
    float acc[8] = {0.f, 0.f, 0.f, 0.f, 0.f, 0.f, 0.f, 0.f};

    auto proc = [&](h16x8 hv, bool ok) {
        h16x8 s = hv + rx;
        h16x8 l = __builtin_elementwise_max(s, s * neg8);
        const h16x2* lp = (const h16x2*)&l;
        float part = dot8_h(lp, a);
        part += __shfl_xor(part, 1);      // head = lane pair (16 ch)
        float p = ok ? __expf(part) : 0.f;
        lrun += p;
        const _Float16* hp = (const _Float16*)&hv;
#pragma unroll
        for (int k = 0; k < 8; k++) acc[k] = fmaf(p, (float)hp[k], acc[k]);
    };

    while (true) {
        int ce = min(end, cb + 16);
        for (int e = cb; e < ce; e += 4) {    // 4 edges in flight per group
            int off = e - cb;
            h16x8 hv[4];
#pragma unroll
            for (int j = 0; j < 4; j++) {
                int u = __shfl(cidx, off + j, 16);   // masked slots -> v
                hv[j] = *(const h16x8*)&xl[((size_t)u << 7) + ch];
            }
#pragma unroll
            for (int j = 0; j < 4; j++) proc(hv[j], e + j < end);
        }
        cb += 16;
        if (cb >= end) break;
        cidx = (cb + L < end) ? col[cb + L] : v;
    }

    // epilogue: denominators/acc complete in-group; folded-BN affine + ELU
    float inv = 1.0f / lrun;
    float4 A0 = *(const float4*)&bnA[ch];
    float4 A1 = *(const float4*)&bnA[ch + 4];
    float4 B0 = *(const float4*)&bnB[ch];
    float4 B1 = *(const float4*)&bnB[ch + 4];
    float Av[8] = {A0.x, A0.y, A0.z, A0.w, A1.x, A1.y, A1.z, A1.w};
    float Bv[8] = {B0.x, B0.y, B0.z, B0.w, B1.x, B1.y, B1.z, B1.w};
    h16x8 outv;
#pragma unroll
    for (int k = 0; k < 8; k++) {
        float o = fmaf(acc[k], inv * Av[k], Bv[k]);
        o = o > 0.f ? o : expm1f(o);
        outv[k] = (_Float16)o;
    }
    *(h16x8*)&oh[((size_t)v << 7) + ch] = outv;
}

// ---------------- final aggregate (4-lane group = node), fp32, HC=16 --------
// 64 nodes/block; H=1 head spans the 4 lanes -> logit reduce xor1+xor2;
// no cross-slot tree; store is 4 lanes x float4 = 64B contiguous.

__global__ __launch_bounds__(256) void agg_f(
    const float* __restrict__ xl, const float* __restrict__ xr,
    const int* __restrict__ rowptr, const int* __restrict__ col,
    const float* __restrict__ att, const float* __restrict__ bias,
    float* __restrict__ out, int n) {
    int v = (blockIdx.x * blockDim.x + threadIdx.x) >> 2;
    if (v >= n) return;
    int L = threadIdx.x & 3;
    int ch = 4 * L;

    int beg = rowptr[v];
    int end = rowptr[v + 1];
    int cb = beg;
    int cidx = (cb + L < end) ? col[cb + L] : v;   // 4-edge window

    float4 xrv = *(const float4*)&xr[((size_t)v << 4) + ch];
    float4 av = *(const float4*)&att[ch];

    float lrun = 0.f;
    float4 acc = make_float4(0.f, 0.f, 0.f, 0.f);

    while (true) {
        float4 xv[4];
#pragma unroll
        for (int j = 0; j < 4; j++) {
            int u = __shfl(cidx, j, 4);            // masked slots -> v
            xv[j] = *(const float4*)&xl[((size_t)u << 4) + ch];
        }
#pragma unroll
        for (int j = 0; j < 4; j++) {
            bool ok = (cb + j < end);
            float s0 = xv[j].x + xrv.x; s0 = s0 > 0.f ? s0 : NEG * s0;
            float s1 = xv[j].y + xrv.y; s1 = s1 > 0.f ? s1 : NEG * s1;
            float s2 = xv[j].z + xrv.z; s2 = s2 > 0.f ? s2 : NEG * s2;
            float s3 = xv[j].w + xrv.w; s3 = s3 > 0.f ? s3 : NEG * s3;
            float part = fmaf(s0, av.x, fmaf(s1, av.y, fmaf(s2, av.z, s3 * av.w)));
            part += __shfl_xor(part, 1);
            part += __shfl_xor(part, 2);
            float p = ok ? __expf(part) : 0.f;
            lrun += p;
            acc.x = fmaf(p, xv[j].x, acc.x);
            acc.y = fmaf(p, xv[j].y, acc.y);
            acc.z = fmaf(p, xv[j].z, acc.z);
            acc.w = fmaf(p, xv[j].w, acc.w);
        }
        cb += 4;
        if (cb >= end) break;
        cidx = (cb + L < end) ? col[cb + L] : v;
    }

    float inv = 1.0f / lrun;
    float4 b4 = *(const float4*)&bias[ch];
    *(float4*)&out[((size_t)v << 4) + ch] =
        make_float4(fmaf(acc.x, inv, b4.x), fmaf(acc.y, inv, b4.y),
                    fmaf(acc.z, inv, b4.z), fmaf(acc.w, inv, b4.w));
}

// ---------------- launch ----------------

extern "C" void kernel_launch(void* const* d_in, const int* in_sizes, int n_in,
                              void* d_out, int out_size, void* d_ws, size_t ws_size,
                              hipStream_t stream) {
    const float* x = (const float*)d_in[0];
    const int* ei = (const int*)d_in[1];
    const float* Wl[4] = {(const float*)d_in[2], (const float*)d_in[6],
                          (const float*)d_in[10], (const float*)d_in[14]};
    const float* Wr[4] = {(const float*)d_in[3], (const float*)d_in[7],
                          (const float*)d_in[11], (const float*)d_in[15]};
    const float* att[4] = {(const float*)d_in[4], (const float*)d_in[8],
                           (const float*)d_in[12], (const float*)d_in[16]};
    const float* bias[4] = {(const float*)d_in[5], (const float*)d_in[9],
                            (const float*)d_in[13], (const float*)d_in[17]};
    const float* g[3] = {(const float*)d_in[18], (const float*)d_in[22], (const float*)d_in[26]};
    const float* be[3] = {(const float*)d_in[19], (const float*)d_in[23], (const float*)d_in[27]};
    const float* bm[3] = {(const float*)d_in[20], (const float*)d_in[24], (const float*)d_in[28]};
    const float* bv[3] = {(const float*)d_in[21], (const float*)d_in[25], (const float*)d_in[29]};

    const int n = in_sizes[0] / 128;
    const int E = in_sizes[1] / 2;
    const int ET = E + n;

    char* p = (char*)d_ws;
    __half* xh = (__half*)p;           p += (size_t)n * 128 * 2;
    __half* xlh = (__half*)p;          p += (size_t)n * 128 * 2;
    __half* xrh = (__half*)p;          p += (size_t)n * 128 * 2;
    float* xl3 = (float*)p;            p += (size_t)n * 16 * 4;
    float* xr3 = (float*)p;            p += (size_t)n * 16 * 4;
    int* rowptr = (int*)p;            p += (size_t)(n + 4) * 4;   // padded for alignment
    int* cnt = (int*)p;               p += (size_t)n * 4;
    int* fill = (int*)p;              p += (size_t)n * 4;   // contiguous after cnt
    int* col = (int*)p;               p += (size_t)ET * 4;
    int* bsums = (int*)p;             p += 256;
    __half* pk[4];
    for (int i = 0; i < 3; i++) { pk[i] = (__half*)p; p += 4 * 16 * 512 * 2; }
    pk[3] = (__half*)p;               p += 4 * 2 * 512 * 2;
    float* bnA = (float*)p;           p += 384 * 4;
    float* bnB = (float*)p;           p += 384 * 4;

    // one memset over cnt+fill (adjacent, 8n bytes)
    (void)hipMemsetAsync(cnt, 0, (size_t)n * 8, stream);

    const int tb = 256;
    const int histBlocks = (ET + tb - 1) / tb;
    hist_pack<<<201 + histBlocks, tb, 0, stream>>>(
        ei, E, n, cnt,
        Wl[0], Wr[0], Wl[1], Wr[1], Wl[2], Wr[2], Wl[3], Wr[3],
        pk[0], pk[1], pk[2], pk[3],
        bias[0], bias[1], bias[2],
        g[0], g[1], g[2], be[0], be[1], be[2],
        bm[0], bm[1], bm[2], bv[0], bv[1], bv[2],
        bnA, bnB);

    const int nb = (n + 1023) / 1024;
    const int gb64 = (n + 63) / 64;
    const int gemmBlocksSmall = ((n + 15) / 16 + 3) / 4;
    const int aggBlocksH = (n + 15) / 16;   // 16-lane group per node
    const int aggBlocksF = (n + 63) / 64;   // 4-lane group per node

    // scan_block co-dispatched with layer-0 GEMM (independent work)
    scanblk_gemm0<<<nb + gb64, 256, 0, stream>>>(
        cnt, rowptr, bsums, n, nb, x, pk[0], xlh, xrh);
    scan_add2<<<nb, 1024, 0, stream>>>(rowptr, bsums, n, nb);
    scatter_kernel<<<(ET + tb - 1) / tb, tb, 0, stream>>>(ei, E, n, rowptr, fill, col);

    agg_h<<<aggBlocksH, 256, 0, stream>>>(
        xlh, xrh, rowptr, col, att[0], bnA, bnB, xh, n);
    for (int i = 1; i < 3; i++) {
        gemm_h_big2<<<gb64, 256, 0, stream>>>(xh, pk[i], xlh, xrh, n);
        agg_h<<<aggBlocksH, 256, 0, stream>>>(
            xlh, xrh, rowptr, col, att[i], bnA + 128 * i, bnB + 128 * i, xh, n);
    }
    gemm_h_small<<<gemmBlocksSmall, 256, 0, stream>>>(xh, pk[3], xl3, xr3, n);
    agg_f<<<aggBlocksF, 256, 0, stream>>>(
        xl3, xr3, rowptr, col, att[3], bias[3], (float*)d_out, n);
}